// Round 8
// baseline (349.274 us; speedup 1.0000x reference)
//
#include <hip/hip_runtime.h>
#include <hip/hip_bf16.h>
#include <cstddef>

// ILA_10986526343542: linear attention block, bf16-MFMA pipeline.
// x:[8,256,128,128] fp32.
//   xTb = bf16(x)^T [b][n][c]                  (xt_pass, XT tier only)
//   ek  = exp(s*(Wk@x+bk)) bf16 [b][c][n]      (proj_mfma<false>, + ksump2)
//   ksum[b,c] = sum ksump2                      (ksum_red)
//   T   = ek @ x^T (8 n-chunks)                 (t_mfma, dbuf gload, 512 blocks)
//   Tred= (sum_chunks T)/ksum  (in-place)       (treduce)
//   ctx = Tred@Wv^T + bv                        (ctx_pass)
//   M   = Wo_h @ ctx_h^T  (bf16)                (mpass)
//   eqT = 1/Z-scaled exp(s*(Wq@x+bq)) bf16 [b][n][c]  (proj_mfma<true>)
//   out = M @ eqT^T + bo                        (out_mfma)

constexpr int   NPIX     = 16384;
constexpr float QK_SCALE = 0.42044820762685725f;  // 32^-0.25

typedef __attribute__((ext_vector_type(8))) short          bf16x8;
typedef __attribute__((ext_vector_type(8))) unsigned short u16x8;
typedef __attribute__((ext_vector_type(4))) float          f32x4;

__device__ __forceinline__ float bf2f(unsigned short v) {
    union { unsigned int u; float f; } c; c.u = ((unsigned int)v) << 16; return c.f;
}
__device__ __forceinline__ unsigned short f2bf(float f) {
    union { __hip_bfloat16 h; unsigned short s; } c; c.h = __float2bfloat16(f); return c.s;
}
// async global->LDS, 16B per lane; dest = wave-uniform base + lane*16
__device__ __forceinline__ void gload_lds16(const void* g, void* l) {
    __builtin_amdgcn_global_load_lds(
        (const __attribute__((address_space(1))) unsigned int*)g,
        (__attribute__((address_space(3))) unsigned int*)l, 16, 0, 0);
}

typedef unsigned short lds_row32[32];

// ---- 0: weights to bf16 ----------------------------------------------------
__global__ __launch_bounds__(256) void prep(
    const float* __restrict__ Wq, const float* __restrict__ Wk,
    unsigned short* __restrict__ Wqb, unsigned short* __restrict__ Wkb)
{
    const int i = blockIdx.x * 256 + threadIdx.x;   // 65536 total
    Wqb[i] = f2bf(Wq[i]);
    Wkb[i] = f2bf(Wk[i]);
}

// ---- 0b: xTb[b][n][c] = bf16(x) transposed (XT tier) -----------------------
__global__ __launch_bounds__(256) void xt_pass(
    const float* __restrict__ x, unsigned short* __restrict__ xTb)
{
    __shared__ float tile[64][65];
    const int b = blockIdx.z, c0 = blockIdx.y * 64, n0 = blockIdx.x * 64;
    const int t = threadIdx.x;
    const int tr = t >> 2, tc = (t & 3) * 16;
    const float* src = x + ((size_t)b*256 + c0 + tr) * NPIX + n0 + tc;
    #pragma unroll
    for (int u = 0; u < 16; u += 4) {
        f32x4 v = *(const f32x4*)(src + u);
        tile[tr][tc+u+0] = v.x; tile[tr][tc+u+1] = v.y;
        tile[tr][tc+u+2] = v.z; tile[tr][tc+u+3] = v.w;
    }
    __syncthreads();
    unsigned short* dst = xTb + ((size_t)b*NPIX + n0 + tr) * 256 + c0 + tc;
    u16x8 p0, p1;
    #pragma unroll
    for (int u = 0; u < 8; ++u) p0[u] = f2bf(tile[tc+u][tr]);
    #pragma unroll
    for (int u = 0; u < 8; ++u) p1[u] = f2bf(tile[tc+8+u][tr]);
    *(u16x8*)dst = p0; *(u16x8*)(dst + 8) = p1;
}

// ---- 1/6: projection via MFMA ---------------------------------------------
// XT=true : A,B via dbuf global_load_lds (A=W rows, B=xTb rows), XOR-swizzled.
// XT=false: A via global_load_lds (swizzled), B via float2 gather -> BsT[128][40].
// Epilogue: Cs bounce. KPASS adds per-row column-sum partials (ksump2).
// QPASS folds per-head 1/Z (pre-scaled eqT, transposed store).
template<bool QPASS, bool XT>
__global__ __launch_bounds__(256) void proj_mfma(
    const float* __restrict__ x, const unsigned short* __restrict__ xTb,
    const unsigned short* __restrict__ Wb, const float* __restrict__ bias,
    unsigned short* __restrict__ eout, float* __restrict__ ksump2)
{
    __shared__ alignas(16) unsigned char smem[36864];
    const int b  = blockIdx.z;
    const int m0 = blockIdx.y * 128;
    const int n0 = blockIdx.x * 128;
    const int t  = threadIdx.x;
    const int w  = t >> 6, l = t & 63;
    const int lm = l & 15, lg = l >> 4;
    const int mwl = (w & 1) * 64;
    const int nwl = (w >> 1) * 64;
    const int lgs = (lg ^ ((lm & 3) ^ ((lm >> 2) & 3))) * 8;
    const int r16 = l >> 2;
    const int scb = (((l & 3) ^ ((r16 & 3) ^ ((r16 >> 2) & 3)))) * 8;

    const unsigned short* Abase = Wb + (size_t)m0 * 256;

    f32x4 acc[4][4] = {};

    if (XT) {
        lds_row32* As0 = (lds_row32*)smem;             // [2][128][32]
        lds_row32* Bs0 = (lds_row32*)(smem + 16384);
        const unsigned short* Bbase = xTb + ((size_t)b*NPIX + n0) * 256;
        auto stage = [&](int buf, int k0) {
            #pragma unroll
            for (int i = 0; i < 2; ++i) {
                const int row0 = w*32 + i*16;
                gload_lds16(Abase + (size_t)(row0 + r16)*256 + k0 + scb,
                            &As0[buf*128 + row0][0]);
                gload_lds16(Bbase + (size_t)(row0 + r16)*256 + k0 + scb,
                            &Bs0[buf*128 + row0][0]);
            }
        };
        stage(0, 0);
        __syncthreads();
        for (int t8 = 0; t8 < 8; ++t8) {
            const int cur = t8 & 1;
            if (t8 < 7) stage(cur ^ 1, (t8 + 1) * 32);
            bf16x8 afr[4], bfr[4];
            #pragma unroll
            for (int i = 0; i < 4; ++i)
                afr[i] = *(const bf16x8*)&As0[cur*128 + mwl + i*16 + lm][lgs];
            #pragma unroll
            for (int j = 0; j < 4; ++j)
                bfr[j] = *(const bf16x8*)&Bs0[cur*128 + nwl + j*16 + lm][lgs];
            #pragma unroll
            for (int i = 0; i < 4; ++i)
                #pragma unroll
                for (int j = 0; j < 4; ++j)
                    acc[i][j] = __builtin_amdgcn_mfma_f32_16x16x32_bf16(afr[i], bfr[j], acc[i][j], 0, 0, 0);
            __syncthreads();
        }
    } else {
        lds_row32* As1 = (lds_row32*)smem;                            // [128][32]
        unsigned short (*BsT)[40] = (unsigned short(*)[40])(smem + 16384);
        const float* xb = x + (size_t)b * 256 * NPIX + n0;
        const int np = (t & 63) * 2, kq = (t >> 6) * 8;
        for (int k0 = 0; k0 < 256; k0 += 32) {
            #pragma unroll
            for (int i = 0; i < 2; ++i) {
                const int row0 = w*32 + i*16;
                gload_lds16(Abase + (size_t)(row0 + r16)*256 + k0 + scb, &As1[row0][0]);
            }
            {   // B: x columns -> transposed LDS tile
                const float* src = xb + (size_t)(k0 + kq) * NPIX + np;
                float2 v[8];
                #pragma unroll
                for (int r = 0; r < 8; ++r)
                    v[r] = *(const float2*)(src + (size_t)r * NPIX);
                u16x8 pa, pb;
                #pragma unroll
                for (int r = 0; r < 8; ++r) { pa[r] = f2bf(v[r].x); pb[r] = f2bf(v[r].y); }
                *(u16x8*)&BsT[np][kq]     = pa;
                *(u16x8*)&BsT[np + 1][kq] = pb;
            }
            __syncthreads();
            bf16x8 afr[4], bfr[4];
            #pragma unroll
            for (int i = 0; i < 4; ++i)
                afr[i] = *(const bf16x8*)&As1[mwl + i*16 + lm][lgs];
            #pragma unroll
            for (int j = 0; j < 4; ++j)
                bfr[j] = *(const bf16x8*)&BsT[nwl + j*16 + lm][lg*8];
            #pragma unroll
            for (int i = 0; i < 4; ++i)
                #pragma unroll
                for (int j = 0; j < 4; ++j)
                    acc[i][j] = __builtin_amdgcn_mfma_f32_16x16x32_bf16(afr[i], bfr[j], acc[i][j], 0, 0, 0);
            __syncthreads();
        }
    }

    // epilogue: exp + bf16 via Cs bounce (aliases loop LDS; loop ends barriered)
    unsigned short (*Cs)[64][72] = (unsigned short(*)[64][72])smem;
    const int mw = m0 + mwl, nw = n0 + nwl;
    float ksloc[4][4];
    #pragma unroll
    for (int i = 0; i < 4; ++i) {
        const f32x4 bb4 = *(const f32x4*)(bias + mw + i*16 + lg*4);
        #pragma unroll
        for (int r = 0; r < 4; ++r) {
            const int row = i*16 + lg*4 + r;
            float cs = 0.f;
            #pragma unroll
            for (int j = 0; j < 4; ++j) {
                const int col = j*16 + lm;
                const unsigned short bs = f2bf(__expf(QK_SCALE * (acc[i][j][r] + bb4[r])));
                if (QPASS) Cs[w][col][row] = bs;   // [n-local][c-local]
                else { Cs[w][row][col] = bs; cs += bf2f(bs); }
            }
            ksloc[i][r] = cs;
        }
    }
    if (!QPASS) {   // per-row sums over this wave's 64 cols -> ksump2
        #pragma unroll
        for (int i = 0; i < 4; ++i)
            #pragma unroll
            for (int r = 0; r < 4; ++r) {
                float v = ksloc[i][r];
                v += __shfl_xor(v, 1, 64);
                v += __shfl_xor(v, 2, 64);
                v += __shfl_xor(v, 4, 64);
                v += __shfl_xor(v, 8, 64);
                if (lm == 0) {
                    const int nt2 = blockIdx.x * 2 + (w >> 1);
                    ksump2[((size_t)b*256 + nt2)*256 + mw + i*16 + lg*4 + r] = v;
                }
            }
    }
    __syncthreads();

    if (QPASS) {
        // pixel l's 64 channels = 2 whole heads: fold 1/Z here (pre-scaled eqT)
        unsigned short* dst = eout + ((size_t)b * NPIX + nw + l) * 256 + mw;
        u16x8 vv[8];
        float z0 = 0.f, z1 = 0.f;
        #pragma unroll
        for (int s8 = 0; s8 < 8; ++s8) {
            vv[s8] = *(const u16x8*)&Cs[w][l][s8*8];
            float ps = 0.f;
            #pragma unroll
            for (int u = 0; u < 8; ++u) ps += bf2f(vv[s8][u]);
            if (s8 < 4) z0 += ps; else z1 += ps;
        }
        const float iz0 = 1.0f / z0, iz1 = 1.0f / z1;
        #pragma unroll
        for (int s8 = 0; s8 < 8; ++s8) {
            const float iz = (s8 < 4) ? iz0 : iz1;
            u16x8 o;
            #pragma unroll
            for (int u = 0; u < 8; ++u) o[u] = f2bf(bf2f(vv[s8][u]) * iz);
            *(u16x8*)(dst + s8*8) = o;
        }
    } else {
        unsigned short* dst = eout + ((size_t)b * 256 + mw + l) * NPIX + nw;
        #pragma unroll
        for (int s8 = 0; s8 < 8; ++s8)
            *(u16x8*)(dst + s8*8) = *(const u16x8*)&Cs[w][l][s8*8];
    }
}

// ---- 1c: ksum[b,c] = sum_nt2 ksump2 ---------------------------------------
__global__ __launch_bounds__(256) void ksum_red(
    const float* __restrict__ ksump2, float* __restrict__ ksum)
{
    const int row = blockIdx.x * 256 + threadIdx.x;  // 0..2047 = b*256 + c
    const int b = row >> 8, c = row & 255;
    float s = 0.f;
    for (int nt = 0; nt < 256; ++nt)
        s += ksump2[((size_t)b*256 + nt)*256 + c];
    ksum[row] = s;
}

// ---- 2: Tpart[b][chunk] = ek @ x^T, dbuf gload, 64m x 128c tiles -----------
__global__ __launch_bounds__(256) void t_mfma(
    const unsigned short* __restrict__ ek, const float* __restrict__ x,
    float* __restrict__ Tpart)
{
    __shared__ alignas(16) unsigned char smem[24576];
    lds_row32* As = (lds_row32*)smem;               // [2][64][32]
    lds_row32* Bs = (lds_row32*)(smem + 8192);      // [2][128][32]
    const int bx = blockIdx.x;            // 0..7: 4 m-tiles x 2 c-tiles
    const int chunk = blockIdx.y, b = blockIdx.z;
    const int mt = (bx >> 1) * 64;
    const int ct = (bx & 1) * 128;
    const int t = threadIdx.x;
    const int w = t >> 6, l = t & 63;
    const int lm = l & 15, lg = l >> 4;
    const int mw = (w & 1) * 32, cw = (w >> 1) * 64;
    const int r16 = l >> 2;
    const int scb = ((l & 3) ^ ((r16 & 3) ^ ((r16 >> 2) & 3))) * 8;
    const int lgs = (lg ^ ((lm & 3) ^ ((lm >> 2) & 3))) * 8;
    const int brq = t >> 3;         // B: row base 0..31
    const int bc4 = (t & 7) * 4;    // B: float offset in 32-float window
    const int bslot = (t & 7) >> 1; // B: 16B slot 0..3
    const int bhalf = (t & 1) * 4;  // B: shorts offset within slot

    const unsigned short* Abase = ek + ((size_t)b*256 + mt) * NPIX;
    const float*          Bbase = x  + ((size_t)b*256 + ct) * NPIX;
    const int p0base = chunk * 2048;

    f32x4 breg[4];
    f32x4 acc[2][4] = {};

    // prologue
    gload_lds16(Abase + (size_t)(w*16 + r16) * NPIX + p0base + scb, &As[0 + w*16][0]);
    #pragma unroll
    for (int it = 0; it < 4; ++it)
        breg[it] = *(const f32x4*)(Bbase + (size_t)(it*32 + brq) * NPIX + p0base + bc4);
    #pragma unroll
    for (int it = 0; it < 4; ++it) {
        const int row = it*32 + brq;
        const int sl = bslot ^ ((row & 3) ^ ((row >> 2) & 3));
        unsigned short o[4] = { f2bf(breg[it].x), f2bf(breg[it].y),
                                f2bf(breg[it].z), f2bf(breg[it].w) };
        *(ushort4*)&Bs[0 + row][sl*8 + bhalf] = *(ushort4*)o;
    }
    __syncthreads();

    for (int t8 = 0; t8 < 64; ++t8) {
        const int cur = t8 & 1;
        if (t8 < 63) {   // issue next-step loads early
            const int p0 = p0base + (t8 + 1) * 32;
            gload_lds16(Abase + (size_t)(w*16 + r16) * NPIX + p0 + scb,
                        &As[(cur^1)*64 + w*16][0]);
            #pragma unroll
            for (int it = 0; it < 4; ++it)
                breg[it] = *(const f32x4*)(Bbase + (size_t)(it*32 + brq) * NPIX + p0 + bc4);
        }
        bf16x8 afr[2], bfr[4];
        #pragma unroll
        for (int i = 0; i < 2; ++i)
            afr[i] = *(const bf16x8*)&As[cur*64 + mw + i*16 + lm][lgs];
        #pragma unroll
        for (int j = 0; j < 4; ++j)
            bfr[j] = *(const bf16x8*)&Bs[cur*128 + cw + j*16 + lm][lgs];
        #pragma unroll
        for (int i = 0; i < 2; ++i)
            #pragma unroll
            for (int j = 0; j < 4; ++j)
                acc[i][j] = __builtin_amdgcn_mfma_f32_16x16x32_bf16(afr[i], bfr[j], acc[i][j], 0, 0, 0);
        if (t8 < 63) {   // cvt + write next B tile
            #pragma unroll
            for (int it = 0; it < 4; ++it) {
                const int row = it*32 + brq;
                const int sl = bslot ^ ((row & 3) ^ ((row >> 2) & 3));
                unsigned short o[4] = { f2bf(breg[it].x), f2bf(breg[it].y),
                                        f2bf(breg[it].z), f2bf(breg[it].w) };
                *(ushort4*)&Bs[(cur^1)*128 + row][sl*8 + bhalf] = *(ushort4*)o;
            }
        }
        __syncthreads();
    }

    float* dst = Tpart + (((size_t)b*8 + chunk) * 256) * 256;
    #pragma unroll
    for (int i = 0; i < 2; ++i)
        #pragma unroll
        for (int r = 0; r < 4; ++r) {
            const int gm = mt + mw + i*16 + lg*4 + r;
            #pragma unroll
            for (int j = 0; j < 4; ++j)
                dst[(size_t)gm * 256 + ct + cw + j*16 + lm] = acc[i][j][r];
        }
}

// ---- 3a: reduce Tpart chunks in place, fold 1/ksum -------------------------
__global__ __launch_bounds__(256) void treduce(
    float* __restrict__ Tpart, const float* __restrict__ ksum)
{
    const int gid = blockIdx.x * 256 + threadIdx.x;
    const int b   = gid >> 14;
    const int rem = gid & 16383;
    const int r   = rem >> 6;
    const int c4  = (rem & 63) * 4;
    float* base = Tpart + (((size_t)b*8) * 256 + r) * 256 + c4;
    f32x4 s = *(f32x4*)base;
    #pragma unroll
    for (int ch = 1; ch < 8; ++ch) {
        f32x4 v = *(const f32x4*)(base + (size_t)ch * 65536);
        s.x += v.x; s.y += v.y; s.z += v.z; s.w += v.w;
    }
    const float inv = 1.0f / ksum[b*256 + r];
    s.x *= inv; s.y *= inv; s.z *= inv; s.w *= inv;
    *(f32x4*)base = s;
}

// ---- 3b: ctx = Tred@Wv^T + bv ---------------------------------------------
__global__ __launch_bounds__(256) void ctx_pass(
    const float* __restrict__ Tpart, const float* __restrict__ Wv,
    const float* __restrict__ bv, float* __restrict__ ctx)
{
    const int gid = blockIdx.x * 256 + threadIdx.x;
    const int b   = gid >> 14;
    const int rem = gid & 16383;
    const int h   = rem >> 11;
    const int de  = rem & 2047;
    const int d   = de >> 6;
    const int e   = de & 63;
    const float* tp = Tpart + (((size_t)b*8) * 256 + h*32 + d) * 256;
    const float* wv = Wv + (size_t)(h*64 + e) * 256;
    float sx = 0.f, sy = 0.f, sz = 0.f, sw = 0.f;
    #pragma unroll 8
    for (int c = 0; c < 256; c += 4) {
        f32x4 a = *(const f32x4*)(tp + c);
        f32x4 wv4 = *(const f32x4*)(wv + c);
        sx = fmaf(a.x, wv4.x, sx); sy = fmaf(a.y, wv4.y, sy);
        sz = fmaf(a.z, wv4.z, sz); sw = fmaf(a.w, wv4.w, sw);
    }
    ctx[gid] = (sx + sy) + (sz + sw) + bv[h*64 + e];
}

// ---- 3c: M = Wo_h @ ctx_h^T (bf16) -----------------------------------------
__global__ __launch_bounds__(256) void mpass(
    const float* __restrict__ ctx, const float* __restrict__ Wo,
    unsigned short* __restrict__ Mb)
{
    const int gid = blockIdx.x * 256 + threadIdx.x;
    const int b   = gid >> 16;
    const int rem = gid & 65535;
    const int o   = rem >> 8;
    const int dg  = rem & 255;
    const int h   = dg >> 5;
    const float* cp = ctx + ((size_t)b*8 + h) * 2048 + (dg & 31) * 64;
    const float* wp = Wo + (size_t)o * 512 + h*64;
    float sx = 0.f, sy = 0.f, sz = 0.f, sw = 0.f;
    #pragma unroll
    for (int e = 0; e < 64; e += 4) {
        f32x4 a = *(const f32x4*)(cp + e);
        f32x4 wv = *(const f32x4*)(wp + e);
        sx = fmaf(a.x, wv.x, sx); sy = fmaf(a.y, wv.y, sy);
        sz = fmaf(a.z, wv.z, sz); sw = fmaf(a.w, wv.w, sw);
    }
    Mb[((size_t)b*256 + o) * 256 + dg] = f2bf((sx + sy) + (sz + sw));
}

// ---- 4: out = M @ eqT^T + bo (dbuf global_load_lds, swizzled) --------------
__global__ __launch_bounds__(256) void out_mfma(
    const unsigned short* __restrict__ eqT, const unsigned short* __restrict__ Mb,
    const float* __restrict__ bo, float* __restrict__ out)
{
    __shared__ alignas(16) unsigned char smem[32768];
    lds_row32* As0 = (lds_row32*)smem;             // [2][128][32]
    lds_row32* Bs0 = (lds_row32*)(smem + 16384);
    const int b  = blockIdx.z;
    const int m0 = blockIdx.y * 128;
    const int n0 = blockIdx.x * 128;
    const int t  = threadIdx.x;
    const int w  = t >> 6, l = t & 63;
    const int lm = l & 15, lg = l >> 4;
    const int mwl = (w & 1) * 64, nwl = (w >> 1) * 64;
    const int lgs = (lg ^ ((lm & 3) ^ ((lm >> 2) & 3))) * 8;
    const int r16 = l >> 2;
    const int scb = (((l & 3) ^ ((r16 & 3) ^ ((r16 >> 2) & 3)))) * 8;

    const unsigned short* Abase = Mb  + ((size_t)b*256 + m0) * 256;
    const unsigned short* Bbase = eqT + ((size_t)b*NPIX + n0) * 256;

    auto stage = [&](int buf, int k0) {
        #pragma unroll
        for (int i = 0; i < 2; ++i) {
            const int row0 = w*32 + i*16;
            gload_lds16(Abase + (size_t)(row0 + r16)*256 + k0 + scb, &As0[buf*128 + row0][0]);
            gload_lds16(Bbase + (size_t)(row0 + r16)*256 + k0 + scb, &Bs0[buf*128 + row0][0]);
        }
    };

    f32x4 acc[4][4] = {};
    stage(0, 0);
    __syncthreads();
    for (int t8 = 0; t8 < 8; ++t8) {
        const int cur = t8 & 1;
        if (t8 < 7) stage(cur ^ 1, (t8 + 1) * 32);
        bf16x8 afr[4], bfr[4];
        #pragma unroll
        for (int i = 0; i < 4; ++i)
            afr[i] = *(const bf16x8*)&As0[cur*128 + mwl + i*16 + lm][lgs];
        #pragma unroll
        for (int j = 0; j < 4; ++j)
            bfr[j] = *(const bf16x8*)&Bs0[cur*128 + nwl + j*16 + lm][lgs];
        #pragma unroll
        for (int i = 0; i < 4; ++i)
            #pragma unroll
            for (int j = 0; j < 4; ++j)
                acc[i][j] = __builtin_amdgcn_mfma_f32_16x16x32_bf16(afr[i], bfr[j], acc[i][j], 0, 0, 0);
        __syncthreads();
    }

    #pragma unroll
    for (int i = 0; i < 4; ++i) {
        const f32x4 bb4 = *(const f32x4*)(bo + m0 + mwl + i*16 + lg*4);
        #pragma unroll
        for (int r = 0; r < 4; ++r) {
            const int gm = m0 + mwl + i*16 + lg*4 + r;
            float* dst = out + ((size_t)b*256 + gm) * NPIX + n0 + nwl;
            #pragma unroll
            for (int j = 0; j < 4; ++j)
                dst[j*16 + lm] = acc[i][j][r] + bb4[r];
        }
    }
}

// ---------------------------------------------------------------------------
extern "C" void kernel_launch(void* const* d_in, const int* in_sizes, int n_in,
                              void* d_out, int out_size, void* d_ws, size_t ws_size,
                              hipStream_t stream)
{
    const float* x  = (const float*)d_in[0];
    const float* Wq = (const float*)d_in[1];
    const float* bq = (const float*)d_in[2];
    const float* Wk = (const float*)d_in[3];
    const float* bk = (const float*)d_in[4];
    const float* Wv = (const float*)d_in[5];
    const float* bv = (const float*)d_in[6];
    const float* Wo = (const float*)d_in[7];
    const float* bo = (const float*)d_in[8];
    float* out = (float*)d_out;
    char* wsb = (char*)d_ws;

    // XT layout (guard 152,901,632 B):
    //   ekq@0 (67,108,864) | xTb@67,108,864 (67,108,864) |
    //   Tpart@134,217,728 (16,777,216; ksump2 [8][256][256] f32 aliased early) |
    //   Mb@150,994,944 (1,048,576) | Wqb@152,043,520 | Wkb@152,174,592 |
    //   ksum@152,305,664 (8,192) | ctx@152,313,856 (524,288) -> 152,838,144
    // Fallback layout (guard 89,399,296 B, proven):
    //   ekq@0 | Tpart@67,108,864 (ksump2 aliased) | ctx@83,886,080 |
    //   ksum@84,410,368 | Mb@88,088,576 | Wqb@89,137,152 | Wkb@89,268,224
    const bool use_xt = ws_size >= (size_t)152901632;
    if (!use_xt && ws_size < (size_t)89399296) return;  // fail loud, not crash

    unsigned short* ekq = (unsigned short*)wsb;
    unsigned short* xTb;
    float *Tpart, *ksump2, *ksum, *ctx;
    unsigned short *Mb, *Wqb, *Wkb;
    if (use_xt) {
        xTb    = (unsigned short*)(wsb + 67108864);
        Tpart  = (float*)(wsb + 134217728);
        ksump2 = (float*)(wsb + 134217728);             // alias, consumed pre-t_mfma
        Mb     = (unsigned short*)(wsb + 150994944);
        Wqb    = (unsigned short*)(wsb + 152043520);
        Wkb    = (unsigned short*)(wsb + 152174592);
        ksum   = (float*)(wsb + 152305664);
        ctx    = (float*)(wsb + 152313856);
    } else {
        xTb    = nullptr;
        Tpart  = (float*)(wsb + 67108864);
        ksump2 = (float*)(wsb + 67108864);              // alias, consumed pre-t_mfma
        ctx    = (float*)(wsb + 83886080);
        ksum   = (float*)(wsb + 84410368);
        Mb     = (unsigned short*)(wsb + 88088576);
        Wqb    = (unsigned short*)(wsb + 89137152);
        Wkb    = (unsigned short*)(wsb + 89268224);
    }

    prep<<<256, 256, 0, stream>>>(Wq, Wk, Wqb, Wkb);
    if (use_xt) {
        xt_pass<<<dim3(256, 4, 8), 256, 0, stream>>>(x, xTb);
        proj_mfma<false, true><<<dim3(128, 2, 8), 256, 0, stream>>>(x, xTb, Wkb, bk, ekq, ksump2);
    } else {
        proj_mfma<false, false><<<dim3(128, 2, 8), 256, 0, stream>>>(x, xTb, Wkb, bk, ekq, ksump2);
    }
    ksum_red <<<8,               256, 0, stream>>>(ksump2, ksum);
    t_mfma   <<<dim3(8, 8, 8),   256, 0, stream>>>(ekq, x, Tpart);
    treduce  <<<512,             256, 0, stream>>>(Tpart, ksum);
    ctx_pass <<<512,             256, 0, stream>>>(Tpart, Wv, bv, ctx);
    mpass    <<<2048,            256, 0, stream>>>(ctx, Wo, Mb);
    if (use_xt) {
        proj_mfma<true, true><<<dim3(128, 2, 8), 256, 0, stream>>>(x, xTb, Wqb, bq, ekq, ksump2);
    } else {
        proj_mfma<true, false><<<dim3(128, 2, 8), 256, 0, stream>>>(x, xTb, Wqb, bq, ekq, ksump2);
    }
    out_mfma<<<dim3(128, 2, 8), 256, 0, stream>>>(ekq, Mb, bo, out);
}

// Round 9
// 253.300 us; speedup vs baseline: 1.3789x; 1.3789x over previous
//
#include <hip/hip_runtime.h>
#include <hip/hip_bf16.h>
#include <cstddef>

// ILA_10986526343542: linear attention block, bf16-MFMA pipeline.
// x:[8,256,128,128] fp32.
//   ek  = exp(s*(Wk@x+bk)) bf16 [b][c][n]      (proj_mfma<false>, + ksump2)
//   ksum[b,c] = sum ksump2                      (ksum_red)
//   T   = ek @ x^T (NCH n-chunks)               (t_mfma<NCH>, XCD-grouped)
//   Tred= (sum_chunks T)/ksum  (in-place)       (treduce<NCH>)
//   ctx = Tred@Wv^T + bv                        (ctx_pass)
//   M   = Wo_h @ ctx_h^T  (bf16)                (mpass)
//   eqT = 1/Z-scaled exp(s*(Wq@x+bq)) bf16 [b][n][c]  (proj_mfma<true>)
//   out = M @ eqT^T + bo                        (out_mfma)

constexpr int   NPIX     = 16384;
constexpr float QK_SCALE = 0.42044820762685725f;  // 32^-0.25

typedef __attribute__((ext_vector_type(8))) short          bf16x8;
typedef __attribute__((ext_vector_type(8))) unsigned short u16x8;
typedef __attribute__((ext_vector_type(4))) float          f32x4;

__device__ __forceinline__ float bf2f(unsigned short v) {
    union { unsigned int u; float f; } c; c.u = ((unsigned int)v) << 16; return c.f;
}
__device__ __forceinline__ unsigned short f2bf(float f) {
    union { __hip_bfloat16 h; unsigned short s; } c; c.h = __float2bfloat16(f); return c.s;
}
// async global->LDS, 16B per lane; dest = wave-uniform base + lane*16
__device__ __forceinline__ void gload_lds16(const void* g, void* l) {
    __builtin_amdgcn_global_load_lds(
        (const __attribute__((address_space(1))) unsigned int*)g,
        (__attribute__((address_space(3))) unsigned int*)l, 16, 0, 0);
}

typedef unsigned short lds_row32[32];   // 64-B LDS row (32 px bf16)

// ---- 0: weights to bf16 ----------------------------------------------------
__global__ __launch_bounds__(256) void prep(
    const float* __restrict__ Wq, const float* __restrict__ Wk,
    unsigned short* __restrict__ Wqb, unsigned short* __restrict__ Wkb)
{
    const int i = blockIdx.x * 256 + threadIdx.x;   // 65536 total
    Wqb[i] = f2bf(Wq[i]);
    Wkb[i] = f2bf(Wk[i]);
}

// ---- 1/6: projection via MFMA (A gload+swizzle, B column-gather -> BsT) ----
// Epilogue: Cs bounce. !QPASS adds per-row column-sum partials (ksump2).
// QPASS folds per-head 1/Z and stores transposed eqT [b][n][c].
template<bool QPASS>
__global__ __launch_bounds__(256) void proj_mfma(
    const float* __restrict__ x, const unsigned short* __restrict__ Wb,
    const float* __restrict__ bias, unsigned short* __restrict__ eout,
    float* __restrict__ ksump2)
{
    __shared__ alignas(16) unsigned char smem[36864];
    lds_row32* As1 = (lds_row32*)smem;                            // [128][32]
    unsigned short (*BsT)[40] = (unsigned short(*)[40])(smem + 16384);
    const int b  = blockIdx.z;
    const int m0 = blockIdx.y * 128;
    const int n0 = blockIdx.x * 128;
    const int t  = threadIdx.x;
    const int w  = t >> 6, l = t & 63;
    const int lm = l & 15, lg = l >> 4;
    const int mwl = (w & 1) * 64;
    const int nwl = (w >> 1) * 64;
    const int lgs = (lg ^ ((lm & 3) ^ ((lm >> 2) & 3))) * 8;
    const int r16 = l >> 2;
    const int scb = ((l & 3) ^ ((r16 & 3) ^ ((r16 >> 2) & 3))) * 8;

    const unsigned short* Abase = Wb + (size_t)m0 * 256;
    const float* xb = x + (size_t)b * 256 * NPIX + n0;
    const int np = (t & 63) * 2, kq = (t >> 6) * 8;

    f32x4 acc[4][4] = {};
    for (int k0 = 0; k0 < 256; k0 += 32) {
        #pragma unroll
        for (int i = 0; i < 2; ++i) {
            const int row0 = w*32 + i*16;
            gload_lds16(Abase + (size_t)(row0 + r16)*256 + k0 + scb, &As1[row0][0]);
        }
        {   // B: x columns -> transposed LDS tile
            const float* src = xb + (size_t)(k0 + kq) * NPIX + np;
            float2 v[8];
            #pragma unroll
            for (int r = 0; r < 8; ++r)
                v[r] = *(const float2*)(src + (size_t)r * NPIX);
            u16x8 pa, pb;
            #pragma unroll
            for (int r = 0; r < 8; ++r) { pa[r] = f2bf(v[r].x); pb[r] = f2bf(v[r].y); }
            *(u16x8*)&BsT[np][kq]     = pa;
            *(u16x8*)&BsT[np + 1][kq] = pb;
        }
        __syncthreads();
        bf16x8 afr[4], bfr[4];
        #pragma unroll
        for (int i = 0; i < 4; ++i)
            afr[i] = *(const bf16x8*)&As1[mwl + i*16 + lm][lgs];
        #pragma unroll
        for (int j = 0; j < 4; ++j)
            bfr[j] = *(const bf16x8*)&BsT[nwl + j*16 + lm][lg*8];
        #pragma unroll
        for (int i = 0; i < 4; ++i)
            #pragma unroll
            for (int j = 0; j < 4; ++j)
                acc[i][j] = __builtin_amdgcn_mfma_f32_16x16x32_bf16(afr[i], bfr[j], acc[i][j], 0, 0, 0);
        __syncthreads();
    }

    // epilogue: exp + bf16 via Cs bounce (aliases loop LDS; loop ends barriered)
    unsigned short (*Cs)[64][72] = (unsigned short(*)[64][72])smem;
    const int mw = m0 + mwl, nw = n0 + nwl;
    float ksloc[4][4];
    #pragma unroll
    for (int i = 0; i < 4; ++i) {
        const f32x4 bb4 = *(const f32x4*)(bias + mw + i*16 + lg*4);
        #pragma unroll
        for (int r = 0; r < 4; ++r) {
            const int row = i*16 + lg*4 + r;
            float cs = 0.f;
            #pragma unroll
            for (int j = 0; j < 4; ++j) {
                const int col = j*16 + lm;
                const unsigned short bs = f2bf(__expf(QK_SCALE * (acc[i][j][r] + bb4[r])));
                if (QPASS) Cs[w][col][row] = bs;   // [n-local][c-local]
                else { Cs[w][row][col] = bs; cs += bf2f(bs); }
            }
            ksloc[i][r] = cs;
        }
    }
    if (!QPASS) {   // per-row sums over this wave's 64 cols -> ksump2
        #pragma unroll
        for (int i = 0; i < 4; ++i)
            #pragma unroll
            for (int r = 0; r < 4; ++r) {
                float v = ksloc[i][r];
                v += __shfl_xor(v, 1, 64);
                v += __shfl_xor(v, 2, 64);
                v += __shfl_xor(v, 4, 64);
                v += __shfl_xor(v, 8, 64);
                if (lm == 0) {
                    const int nt2 = blockIdx.x * 2 + (w >> 1);
                    ksump2[((size_t)b*256 + nt2)*256 + mw + i*16 + lg*4 + r] = v;
                }
            }
    }
    __syncthreads();

    if (QPASS) {
        unsigned short* dst = eout + ((size_t)b * NPIX + nw + l) * 256 + mw;
        u16x8 vv[8];
        float z0 = 0.f, z1 = 0.f;
        #pragma unroll
        for (int s8 = 0; s8 < 8; ++s8) {
            vv[s8] = *(const u16x8*)&Cs[w][l][s8*8];
            float ps = 0.f;
            #pragma unroll
            for (int u = 0; u < 8; ++u) ps += bf2f(vv[s8][u]);
            if (s8 < 4) z0 += ps; else z1 += ps;
        }
        const float iz0 = 1.0f / z0, iz1 = 1.0f / z1;
        #pragma unroll
        for (int s8 = 0; s8 < 8; ++s8) {
            const float iz = (s8 < 4) ? iz0 : iz1;
            u16x8 o;
            #pragma unroll
            for (int u = 0; u < 8; ++u) o[u] = f2bf(bf2f(vv[s8][u]) * iz);
            *(u16x8*)(dst + s8*8) = o;
        }
    } else {
        unsigned short* dst = eout + ((size_t)b * 256 + mw + l) * NPIX + nw;
        #pragma unroll
        for (int s8 = 0; s8 < 8; ++s8)
            *(u16x8*)(dst + s8*8) = *(const u16x8*)&Cs[w][l][s8*8];
    }
}

// ---- 1c: ksum[b,c] = sum_nt2 ksump2 (64 blocks, 8 lanes/row) ---------------
__global__ __launch_bounds__(256) void ksum_red(
    const float* __restrict__ ksump2, float* __restrict__ ksum)
{
    const int t = threadIdx.x;
    const int row = blockIdx.x * 32 + (t >> 3);      // 0..2047 = b*256 + c
    const int b = row >> 8, c = row & 255;
    const int nt0 = t & 7;
    float s = 0.f;
    #pragma unroll 8
    for (int i = 0; i < 32; ++i)
        s += ksump2[((size_t)b*256 + nt0 + 8*i)*256 + c];
    s += __shfl_xor(s, 1, 64);
    s += __shfl_xor(s, 2, 64);
    s += __shfl_xor(s, 4, 64);
    if (nt0 == 0) ksum[row] = s;
}

// ---- 2: Tpart[b][chunk] = ek @ x^T, 128x128 tiles, dbuf, XCD-grouped -------
template<int NCH>
__global__ __launch_bounds__(256) void t_mfma(
    const unsigned short* __restrict__ ek, const float* __restrict__ x,
    float* __restrict__ Tpart)
{
    __shared__ alignas(16) unsigned char smem[32768];
    lds_row32* As = (lds_row32*)smem;               // [2][128][32]
    lds_row32* Bs = (lds_row32*)(smem + 16384);     // [2][128][32]
    // XCD grouping: the 4 quads of one (b,chunk) land on the same XCD (%8)
    const int bid  = blockIdx.x;
    const int v    = bid & 7, s = bid >> 3;
    const int gidx = s >> 2, q = s & 3;
    const int group = v + 8 * gidx;                 // 0 .. 8*NCH-1
    const int b = group / NCH, chunk = group % NCH;
    const int mt = (q >> 1) * 128, ct = (q & 1) * 128;
    constexpr int CHPX = NPIX / NCH;

    const int t = threadIdx.x;
    const int w = t >> 6, l = t & 63;
    const int lm = l & 15, lg = l >> 4;
    const int mw = (w & 1) * 64, cw = (w >> 1) * 64;
    const int r16 = l >> 2;
    const int scb = ((l & 3) ^ ((r16 & 3) ^ ((r16 >> 2) & 3))) * 8;
    const int lgs = (lg ^ ((lm & 3) ^ ((lm >> 2) & 3))) * 8;
    const int brq = t >> 3;          // B: row base 0..31 (x4 -> 128 rows)
    const int bc4 = (t & 7) * 4;
    const int bslot = (t & 7) >> 1;
    const int bhalf = (t & 1) * 4;

    const unsigned short* Abase = ek + ((size_t)b*256 + mt) * NPIX;
    const float*          Bbase = x  + ((size_t)b*256 + ct) * NPIX;
    const int p0base = chunk * CHPX;

    f32x4 breg[4];
    f32x4 acc[4][4] = {};

    // prologue: stage step 0
    #pragma unroll
    for (int i = 0; i < 2; ++i) {
        const int row0 = w*32 + i*16;
        gload_lds16(Abase + (size_t)(row0 + r16) * NPIX + p0base + scb, &As[row0][0]);
    }
    #pragma unroll
    for (int it = 0; it < 4; ++it)
        breg[it] = *(const f32x4*)(Bbase + (size_t)(it*32 + brq) * NPIX + p0base + bc4);
    #pragma unroll
    for (int it = 0; it < 4; ++it) {
        const int row = it*32 + brq;
        const int sl = bslot ^ ((row & 3) ^ ((row >> 2) & 3));
        unsigned short o[4] = { f2bf(breg[it].x), f2bf(breg[it].y),
                                f2bf(breg[it].z), f2bf(breg[it].w) };
        *(ushort4*)&Bs[row][sl*8 + bhalf] = *(ushort4*)o;
    }
    __syncthreads();

    constexpr int ITERS = CHPX / 32;
    for (int t8 = 0; t8 < ITERS; ++t8) {
        const int cur = t8 & 1;
        if (t8 < ITERS - 1) {   // issue next-step loads early
            const int p0 = p0base + (t8 + 1) * 32;
            #pragma unroll
            for (int i = 0; i < 2; ++i) {
                const int row0 = w*32 + i*16;
                gload_lds16(Abase + (size_t)(row0 + r16) * NPIX + p0 + scb,
                            &As[(cur^1)*128 + row0][0]);
            }
            #pragma unroll
            for (int it = 0; it < 4; ++it)
                breg[it] = *(const f32x4*)(Bbase + (size_t)(it*32 + brq) * NPIX + p0 + bc4);
        }
        bf16x8 afr[4], bfr[4];
        #pragma unroll
        for (int i = 0; i < 4; ++i)
            afr[i] = *(const bf16x8*)&As[cur*128 + mw + i*16 + lm][lgs];
        #pragma unroll
        for (int j = 0; j < 4; ++j)
            bfr[j] = *(const bf16x8*)&Bs[cur*128 + cw + j*16 + lm][lgs];
        #pragma unroll
        for (int i = 0; i < 4; ++i)
            #pragma unroll
            for (int j = 0; j < 4; ++j)
                acc[i][j] = __builtin_amdgcn_mfma_f32_16x16x32_bf16(afr[i], bfr[j], acc[i][j], 0, 0, 0);
        if (t8 < ITERS - 1) {   // cvt + write next B tile
            #pragma unroll
            for (int it = 0; it < 4; ++it) {
                const int row = it*32 + brq;
                const int sl = bslot ^ ((row & 3) ^ ((row >> 2) & 3));
                unsigned short o[4] = { f2bf(breg[it].x), f2bf(breg[it].y),
                                        f2bf(breg[it].z), f2bf(breg[it].w) };
                *(ushort4*)&Bs[(cur^1)*128 + row][sl*8 + bhalf] = *(ushort4*)o;
            }
        }
        __syncthreads();
    }

    float* dst = Tpart + ((size_t)(b*NCH + chunk) * 256) * 256;
    #pragma unroll
    for (int i = 0; i < 4; ++i)
        #pragma unroll
        for (int r = 0; r < 4; ++r) {
            const int gm = mt + mw + i*16 + lg*4 + r;
            #pragma unroll
            for (int j = 0; j < 4; ++j)
                dst[(size_t)gm * 256 + ct + cw + j*16 + lm] = acc[i][j][r];
        }
}

// ---- 3a: reduce Tpart chunks in place, fold 1/ksum -------------------------
template<int NCH>
__global__ __launch_bounds__(256) void treduce(
    float* __restrict__ Tpart, const float* __restrict__ ksum)
{
    const int gid = blockIdx.x * 256 + threadIdx.x;
    const int b   = gid >> 14;
    const int rem = gid & 16383;
    const int r   = rem >> 6;
    const int c4  = (rem & 63) * 4;
    float* base = Tpart + (((size_t)b*NCH) * 256 + r) * 256 + c4;
    f32x4 s = *(f32x4*)base;
    #pragma unroll
    for (int ch = 1; ch < NCH; ++ch) {
        f32x4 v = *(const f32x4*)(base + (size_t)ch * 65536);
        s.x += v.x; s.y += v.y; s.z += v.z; s.w += v.w;
    }
    const float inv = 1.0f / ksum[b*256 + r];
    s.x *= inv; s.y *= inv; s.z *= inv; s.w *= inv;
    *(f32x4*)base = s;
}

// ---- 3b: ctx = Tred@Wv^T + bv ---------------------------------------------
template<int NCH>
__global__ __launch_bounds__(256) void ctx_pass(
    const float* __restrict__ Tpart, const float* __restrict__ Wv,
    const float* __restrict__ bv, float* __restrict__ ctx)
{
    const int gid = blockIdx.x * 256 + threadIdx.x;
    const int b   = gid >> 14;
    const int rem = gid & 16383;
    const int h   = rem >> 11;
    const int de  = rem & 2047;
    const int d   = de >> 6;
    const int e   = de & 63;
    const float* tp = Tpart + (((size_t)b*NCH) * 256 + h*32 + d) * 256;
    const float* wv = Wv + (size_t)(h*64 + e) * 256;
    float sx = 0.f, sy = 0.f, sz = 0.f, sw = 0.f;
    #pragma unroll 8
    for (int c = 0; c < 256; c += 4) {
        f32x4 a = *(const f32x4*)(tp + c);
        f32x4 wv4 = *(const f32x4*)(wv + c);
        sx = fmaf(a.x, wv4.x, sx); sy = fmaf(a.y, wv4.y, sy);
        sz = fmaf(a.z, wv4.z, sz); sw = fmaf(a.w, wv4.w, sw);
    }
    ctx[gid] = (sx + sy) + (sz + sw) + bv[h*64 + e];
}

// ---- 3c: M = Wo_h @ ctx_h^T (bf16) -----------------------------------------
__global__ __launch_bounds__(256) void mpass(
    const float* __restrict__ ctx, const float* __restrict__ Wo,
    unsigned short* __restrict__ Mb)
{
    const int gid = blockIdx.x * 256 + threadIdx.x;
    const int b   = gid >> 16;
    const int rem = gid & 65535;
    const int o   = rem >> 8;
    const int dg  = rem & 255;
    const int h   = dg >> 5;
    const float* cp = ctx + ((size_t)b*8 + h) * 2048 + (dg & 31) * 64;
    const float* wp = Wo + (size_t)o * 512 + h*64;
    float sx = 0.f, sy = 0.f, sz = 0.f, sw = 0.f;
    #pragma unroll
    for (int e = 0; e < 64; e += 4) {
        f32x4 a = *(const f32x4*)(cp + e);
        f32x4 wv = *(const f32x4*)(wp + e);
        sx = fmaf(a.x, wv.x, sx); sy = fmaf(a.y, wv.y, sy);
        sz = fmaf(a.z, wv.z, sz); sw = fmaf(a.w, wv.w, sw);
    }
    Mb[((size_t)b*256 + o) * 256 + dg] = f2bf((sx + sy) + (sz + sw));
}

// ---- 4: out = M @ eqT^T + bo (dbuf global_load_lds, swizzled) --------------
__global__ __launch_bounds__(256) void out_mfma(
    const unsigned short* __restrict__ eqT, const unsigned short* __restrict__ Mb,
    const float* __restrict__ bo, float* __restrict__ out)
{
    __shared__ alignas(16) unsigned char smem[32768];
    lds_row32* As0 = (lds_row32*)smem;             // [2][128][32]
    lds_row32* Bs0 = (lds_row32*)(smem + 16384);
    const int b  = blockIdx.z;
    const int m0 = blockIdx.y * 128;
    const int n0 = blockIdx.x * 128;
    const int t  = threadIdx.x;
    const int w  = t >> 6, l = t & 63;
    const int lm = l & 15, lg = l >> 4;
    const int mwl = (w & 1) * 64, nwl = (w >> 1) * 64;
    const int lgs = (lg ^ ((lm & 3) ^ ((lm >> 2) & 3))) * 8;
    const int r16 = l >> 2;
    const int scb = ((l & 3) ^ ((r16 & 3) ^ ((r16 >> 2) & 3))) * 8;

    const unsigned short* Abase = Mb  + ((size_t)b*256 + m0) * 256;
    const unsigned short* Bbase = eqT + ((size_t)b*NPIX + n0) * 256;

    auto stage = [&](int buf, int k0) {
        #pragma unroll
        for (int i = 0; i < 2; ++i) {
            const int row0 = w*32 + i*16;
            gload_lds16(Abase + (size_t)(row0 + r16)*256 + k0 + scb, &As0[buf*128 + row0][0]);
            gload_lds16(Bbase + (size_t)(row0 + r16)*256 + k0 + scb, &Bs0[buf*128 + row0][0]);
        }
    };

    f32x4 acc[4][4] = {};
    stage(0, 0);
    __syncthreads();
    for (int t8 = 0; t8 < 8; ++t8) {
        const int cur = t8 & 1;
        if (t8 < 7) stage(cur ^ 1, (t8 + 1) * 32);
        bf16x8 afr[4], bfr[4];
        #pragma unroll
        for (int i = 0; i < 4; ++i)
            afr[i] = *(const bf16x8*)&As0[cur*128 + mwl + i*16 + lm][lgs];
        #pragma unroll
        for (int j = 0; j < 4; ++j)
            bfr[j] = *(const bf16x8*)&Bs0[cur*128 + nwl + j*16 + lm][lgs];
        #pragma unroll
        for (int i = 0; i < 4; ++i)
            #pragma unroll
            for (int j = 0; j < 4; ++j)
                acc[i][j] = __builtin_amdgcn_mfma_f32_16x16x32_bf16(afr[i], bfr[j], acc[i][j], 0, 0, 0);
        __syncthreads();
    }

    #pragma unroll
    for (int i = 0; i < 4; ++i) {
        const f32x4 bb4 = *(const f32x4*)(bo + m0 + mwl + i*16 + lg*4);
        #pragma unroll
        for (int r = 0; r < 4; ++r) {
            const int gm = m0 + mwl + i*16 + lg*4 + r;
            float* dst = out + ((size_t)b*256 + gm) * NPIX + n0 + nwl;
            #pragma unroll
            for (int j = 0; j < 4; ++j)
                dst[j*16 + lm] = acc[i][j][r] + bb4[r];
        }
    }
}

// ---------------------------------------------------------------------------
extern "C" void kernel_launch(void* const* d_in, const int* in_sizes, int n_in,
                              void* d_out, int out_size, void* d_ws, size_t ws_size,
                              hipStream_t stream)
{
    const float* x  = (const float*)d_in[0];
    const float* Wq = (const float*)d_in[1];
    const float* bq = (const float*)d_in[2];
    const float* Wk = (const float*)d_in[3];
    const float* bk = (const float*)d_in[4];
    const float* Wv = (const float*)d_in[5];
    const float* bv = (const float*)d_in[6];
    const float* Wo = (const float*)d_in[7];
    const float* bo = (const float*)d_in[8];
    float* out = (float*)d_out;
    char* wsb = (char*)d_ws;

    // Big layout (guard 102,506,496 B), NCH=16:
    //   ekq@0 (67,108,864) | Tpart@67,108,864 (33,554,432; ksump2 2MB aliased
    //   early, consumed by ksum_red before t_mfma) | ctx@100,663,296 (524,288) |
    //   ksum@101,187,584 (8,192) | Mb@101,195,776 (1,048,576) |
    //   Wqb@102,244,352 | Wkb@102,375,424 -> 102,506,496
    // Small layout (guard 89,399,296 B, proven), NCH=8:
    //   ekq@0 | Tpart/ksump2@67,108,864 (16,777,216) | ctx@83,886,080 |
    //   ksum@84,410,368 | Mb@88,088,576 | Wqb@89,137,152 | Wkb@89,268,224
    const bool big = ws_size >= (size_t)102506496;
    if (!big && ws_size < (size_t)89399296) return;  // fail loud, not crash

    unsigned short* ekq = (unsigned short*)wsb;
    float *Tpart, *ksump2, *ksum, *ctx;
    unsigned short *Mb, *Wqb, *Wkb;
    if (big) {
        Tpart  = (float*)(wsb + 67108864);
        ksump2 = (float*)(wsb + 67108864);
        ctx    = (float*)(wsb + 100663296);
        ksum   = (float*)(wsb + 101187584);
        Mb     = (unsigned short*)(wsb + 101195776);
        Wqb    = (unsigned short*)(wsb + 102244352);
        Wkb    = (unsigned short*)(wsb + 102375424);
    } else {
        Tpart  = (float*)(wsb + 67108864);
        ksump2 = (float*)(wsb + 67108864);
        ctx    = (float*)(wsb + 83886080);
        ksum   = (float*)(wsb + 84410368);
        Mb     = (unsigned short*)(wsb + 88088576);
        Wqb    = (unsigned short*)(wsb + 89137152);
        Wkb    = (unsigned short*)(wsb + 89268224);
    }

    prep            <<<256,             256, 0, stream>>>(Wq, Wk, Wqb, Wkb);
    proj_mfma<false><<<dim3(128, 2, 8), 256, 0, stream>>>(x, Wkb, bk, ekq, ksump2);
    ksum_red        <<<64,              256, 0, stream>>>(ksump2, ksum);
    if (big) {
        t_mfma<16> <<<512, 256, 0, stream>>>(ekq, x, Tpart);
        treduce<16><<<512, 256, 0, stream>>>(Tpart, ksum);
        ctx_pass<16><<<512, 256, 0, stream>>>(Tpart, Wv, bv, ctx);
    } else {
        t_mfma<8>  <<<256, 256, 0, stream>>>(ekq, x, Tpart);
        treduce<8> <<<512, 256, 0, stream>>>(Tpart, ksum);
        ctx_pass<8><<<512, 256, 0, stream>>>(Tpart, Wv, bv, ctx);
    }
    mpass           <<<2048,            256, 0, stream>>>(ctx, Wo, Mb);
    proj_mfma<true> <<<dim3(128, 2, 8), 256, 0, stream>>>(x, Wqb, bq, ekq, ksump2);
    out_mfma        <<<dim3(128, 2, 8), 256, 0, stream>>>(ekq, Mb, bo, out);
}